// Round 10
// baseline (3983.131 us; speedup 1.0000x reference)
//
#include <hip/hip_runtime.h>
#include <cstddef>

#define NN 512
#define BSZ 128
#define TMAXN 1024
#define STEP_F 0.01f
#define EPS_F 1e-05f
#define MATSZ (NN*NN)        // 262144
#define MAT2 (2*MATSZ)
#define OUT_TN (TMAXN*NN)    // 524288
#define SKEW_SCALE 0.03125f  // 2^-5, 5 squarings
#define NBLOCKS 64           // 8 doms x 8 row-groups
#define NDOM 8

typedef __bf16 bf16x8 __attribute__((ext_vector_type(8)));
typedef float f32x4 __attribute__((ext_vector_type(4)));
typedef unsigned short u16x4 __attribute__((ext_vector_type(4)));
typedef unsigned long long ull;

// ---------------- small prep kernels ----------------

__global__ void prep_params(const float* __restrict__ A_raw,
                            const float* __restrict__ Theta_raw,
                            const float* __restrict__ Sigma_raw,
                            const float* __restrict__ bx_raw,
                            float* __restrict__ params,
                            float* __restrict__ theta,
                            float* __restrict__ sigma,
                            float* __restrict__ bx)
{
    int i = threadIdx.x;  // 512 threads
    if (i == 0) params[0] = fabsf(A_raw[0]) + EPS_F;
    theta[i] = fabsf(Theta_raw[i*NN + i]) + EPS_F;
    float sd = Sigma_raw[i*NN + i];
    sigma[i] = expf(-sd*sd);           // (1/G)*exp(-d^2), G=1
    bx[i] = bx_raw[i];
}

// S[z][i][j] = skew(raw_z)[i][j] * 2^-5
__global__ void build_S(const float* __restrict__ U_raw,
                        const float* __restrict__ V_raw,
                        float* __restrict__ S)
{
    int idx = blockIdx.x * 256 + threadIdx.x;   // 0 .. MAT2-1
    int z = idx >> 18;
    int rem = idx & (MATSZ - 1);
    int i = rem >> 9;
    int j = rem & (NN - 1);
    const float* src = (z == 0) ? U_raw : V_raw;
    float v = 0.0f;
    if (i < j)      v = src[i*NN + j];
    else if (i > j) v = -src[j*NN + i];
    S[idx] = v * SKEW_SCALE;
}

// ---------------- fp32 matmul: C = A*B (+C if accflag), batched over z ----------------
// 64x64 tile (round-0-proven body), 256 threads, 4x4/thread, BK=16; 128 blocks/launch
__global__ __launch_bounds__(256) void mm64(const float* __restrict__ A,
                                            const float* __restrict__ Bm,
                                            float* __restrict__ C,
                                            int accflag)
{
    int z = blockIdx.z;
    A  += (size_t)z * MATSZ;
    Bm += (size_t)z * MATSZ;
    C  += (size_t)z * MATSZ;

    __shared__ float As[16][68];   // [k][m], padded
    __shared__ float Bs[16][68];   // [k][n]

    int tid = threadIdx.x;
    int tx = tid & 15;
    int ty = tid >> 4;
    int row0 = blockIdx.y * 64;
    int col0 = blockIdx.x * 64;

    float acc[4][4] = {{0.f}};

    for (int k0 = 0; k0 < NN; k0 += 16) {
        {
            int i = tid >> 2;             // 0..63 row
            int j = (tid & 3) << 2;       // 0,4,8,12 k
            float4 av = *reinterpret_cast<const float4*>(&A[(size_t)(row0 + i)*NN + k0 + j]);
            As[j+0][i] = av.x; As[j+1][i] = av.y; As[j+2][i] = av.z; As[j+3][i] = av.w;
        }
        {
            int bi = tid >> 4;            // 0..15 k
            int bj = (tid & 15) << 2;     // 0..60 col
            float4 bv = *reinterpret_cast<const float4*>(&Bm[(size_t)(k0 + bi)*NN + col0 + bj]);
            *reinterpret_cast<float4*>(&Bs[bi][bj]) = bv;
        }
        __syncthreads();
#pragma unroll
        for (int k = 0; k < 16; ++k) {
            float a0 = As[k][ty], a1 = As[k][ty+16], a2 = As[k][ty+32], a3 = As[k][ty+48];
            float b0 = Bs[k][tx], b1 = Bs[k][tx+16], b2 = Bs[k][tx+32], b3 = Bs[k][tx+48];
            acc[0][0] += a0*b0; acc[0][1] += a0*b1; acc[0][2] += a0*b2; acc[0][3] += a0*b3;
            acc[1][0] += a1*b0; acc[1][1] += a1*b1; acc[1][2] += a1*b2; acc[1][3] += a1*b3;
            acc[2][0] += a2*b0; acc[2][1] += a2*b1; acc[2][2] += a2*b2; acc[2][3] += a2*b3;
            acc[3][0] += a3*b0; acc[3][1] += a3*b1; acc[3][2] += a3*b2; acc[3][3] += a3*b3;
        }
        __syncthreads();
    }

#pragma unroll
    for (int mi = 0; mi < 4; ++mi) {
        size_t r = (size_t)(row0 + ty + 16*mi);
#pragma unroll
        for (int mj = 0; mj < 4; ++mj) {
            size_t cidx = r*NN + col0 + tx + 16*mj;
            float v = acc[mi][mj];
            if (accflag) v += C[cidx];
            C[cidx] = v;
        }
    }
}

// Q0/Q1/Q2 for Paterson-Stockmeyer order-12 Taylor of exp
__global__ void combo3(const float* __restrict__ S, const float* __restrict__ S2,
                       const float* __restrict__ S3, const float* __restrict__ S4,
                       float* __restrict__ Q0, float* __restrict__ Q1,
                       float* __restrict__ Q2)
{
    const float C0 = 1.0f, C1 = 1.0f, C2 = 0.5f, C3 = 1.0f/6.0f;
    const float C4 = 1.0f/24.0f, C5 = 1.0f/120.0f, C6 = 1.0f/720.0f, C7 = 1.0f/5040.0f;
    const float C8 = 1.0f/40320.0f, C9 = 1.0f/362880.0f, C10 = 1.0f/3628800.0f;
    const float C11 = 1.0f/39916800.0f, C12 = 1.0f/479001600.0f;
    int idx = blockIdx.x * 256 + threadIdx.x;   // 0 .. MAT2-1
    int rem = idx & (MATSZ - 1);
    int i = rem >> 9;
    int j = rem & (NN - 1);
    float d = (i == j) ? 1.0f : 0.0f;
    float s = S[idx], s2 = S2[idx], s3 = S3[idx], s4 = S4[idx];
    Q0[idx] = C0*d + C1*s + C2*s2 + C3*s3;
    Q1[idx] = C4*d + C5*s + C6*s2 + C7*s3;
    Q2[idx] = C8*d + C9*s + C10*s2 + C11*s3 + C12*s4;
}

// Asc[i][j] = E_U[i][j]*sigma[j];  VT[i][j] = E_V[j][i]
__global__ void scale_transpose(const float* __restrict__ EU,
                                const float* __restrict__ EV,
                                const float* __restrict__ sigma,
                                float* __restrict__ Asc,
                                float* __restrict__ VT)
{
    int idx = blockIdx.x * 256 + threadIdx.x;   // 0..MATSZ-1
    int i = idx >> 9;
    int j = idx & (NN - 1);
    Asc[idx] = EU[idx] * sigma[j];
    VT[idx]  = EV[j*NN + i];
}

// Bh/Bl[r][k]: bf16 hi/lo split of B[r][k] = Bmm[r][k]*theta[k]/theta[r]
__global__ void finalize_Bsplit(const float* __restrict__ Bmm,
                                const float* __restrict__ theta,
                                __bf16* __restrict__ Bh,
                                __bf16* __restrict__ Bl)
{
    int idx = blockIdx.x * 256 + threadIdx.x;   // 0..MATSZ-1
    int r = idx >> 9;
    int k = idx & (NN - 1);
    float v = Bmm[idx] * theta[k] / theta[r];
    __bf16 h = (__bf16)v;
    Bh[idx] = h;
    Bl[idx] = (__bf16)(v - (float)h);
}

// xb0 = X0 (layout [b][n]); out[b, 0, n] = X0[b][n]
__global__ void init_x(const float* __restrict__ X0,
                       float* __restrict__ xb0,
                       float* __restrict__ out)
{
    int idx = blockIdx.x * 256 + threadIdx.x;   // 0..65535
    int b = idx >> 9;
    int n = idx & (NN - 1);
    float v = X0[idx];
    xb0[idx] = v;
    out[(size_t)b * OUT_TN + n] = v;
}

// ---------------- persistent step kernel (cooperative) ----------------
// 64 blocks x 256 threads (4 waves). dom = bid>>3 owns 16 REAL batch cols
// (no MFMA padding waste); rg = bid&7 owns 64 rows. Wave w: 16-row tile at
// rg*64 + w*16, 16 cols, K=512 (B streamed from L2, ~128KB/block/step).
// Exchange: publish == the trajectory write itself -- 8B agent-atomic stores
// to out[col][t][row] (fresh address every t: NO overwrite hazard). r8-proven
// flag protocol: syncthreads drains publishes, tid0 flags, all threads poll
// one 64B flag line (8 rg), then fetch sibling x_t straight from out (14x8B
// atomic loads/thread), relu+split, unpack to swizzled LDS.
__global__ __launch_bounds__(256, 2) void step_persist(
    const float* __restrict__ x0g,    // [128][512] state at t=0
    const __bf16* __restrict__ Bh,    // [512][512] row-major [r][k]
    const __bf16* __restrict__ Bl,
    const float* __restrict__ params,
    const float* __restrict__ bx,
    float* __restrict__ out,
    unsigned* __restrict__ flg)       // [8 doms][16] u32 (64B line per dom)
{
    // LDS: 2 parity x (hi 16KB + lo 16KB); [col][k] 2B, XOR-swizzled
    __shared__ char xs[65536];
    int tid = threadIdx.x;
    int bid = blockIdx.x;
    int dom = bid >> 3;
    int rg  = bid & 7;
    int w = tid >> 6;
    int l = tid & 63;

    int r0 = rg*64 + w*16;
    int arow = l & 15;
    int kch  = l >> 4;
    const __bf16* bhrow = Bh + (size_t)(r0 + arow)*NN + kch*8;
    const __bf16* blrow = Bl + (size_t)(r0 + arow)*NN + kch*8;

    int c_l  = l & 15;
    int crow = r0 + (l >> 4)*4;          // multiple of 4
    int ccol = dom*16 + c_l;
    float c0 = 1.0f - STEP_F * (params[0]);
    float4 bv = *reinterpret_cast<const float4*>(&bx[crow]);
    int xsw   = (c_l & 7) << 4;
    int xfrag = c_l * 1024;
    int own_ad = xfrag + ((2*crow) ^ xsw);   // 8B-aligned

    // staging/fetch mapping: col = tid>>4, lane-pair index = tid&15
    int sc = tid >> 4;                   // 0..15
    int kl = tid & 15;
    int scb = sc * 1024;
    int ssw = (sc & 7) << 4;

    // ---- prologue: stage full x0 (16 cols x 512 rows) into buf0 ----
    {
        const float* src = x0g + (size_t)(dom*16 + sc)*NN;
#pragma unroll
        for (int i = 0; i < 16; ++i) {
            int k2 = i*32 + kl*2;        // even k, pairs (k2, k2+1)
            float2 v = *reinterpret_cast<const float2*>(&src[k2]);
            float a0 = fmaxf(v.x, 0.f), a1 = fmaxf(v.y, 0.f);
            __bf16 h0 = (__bf16)a0, h1 = (__bf16)a1;
            __bf16 l0 = (__bf16)(a0 - (float)h0), l1 = (__bf16)(a1 - (float)h1);
            unsigned hw = (unsigned)__builtin_bit_cast(unsigned short, h0)
                        | ((unsigned)__builtin_bit_cast(unsigned short, h1) << 16);
            unsigned lw = (unsigned)__builtin_bit_cast(unsigned short, l0)
                        | ((unsigned)__builtin_bit_cast(unsigned short, l1) << 16);
            int ad = scb + ((2*k2) ^ ssw);
            *reinterpret_cast<unsigned*>(&xs[ad]) = hw;
            *reinterpret_cast<unsigned*>(&xs[16384 + ad]) = lw;
        }
    }
    float4 xo = *reinterpret_cast<const float4*>(&x0g[(size_t)ccol*NN + crow]);

    unsigned* fline = flg + dom*16;

    for (int t = 1; t < TMAXN; ++t) {
        __syncthreads();                 // buf[(t-1)&1] fully staged

        int curoff = ((t-1) & 1) * 32768;
        int nxtoff = (t & 1) * 32768;

        // ---- MFMA: acc = B * relu(x_{t-1}) with hi/lo compensation ----
        f32x4 acc0 = {0,0,0,0}, acc1 = {0,0,0,0}, acc2 = {0,0,0,0};
#pragma unroll
        for (int ks = 0; ks < 16; ++ks) {
            bf16x8 ah = *reinterpret_cast<const bf16x8*>(bhrow + ks*32);
            bf16x8 al = *reinterpret_cast<const bf16x8*>(blrow + ks*32);
            int ad = curoff + xfrag + (((ks*32 + kch*8) * 2) ^ xsw);
            bf16x8 xh = *reinterpret_cast<const bf16x8*>(&xs[ad]);
            bf16x8 xl = *reinterpret_cast<const bf16x8*>(&xs[16384 + ad]);
            acc0 = __builtin_amdgcn_mfma_f32_16x16x32_bf16(ah, xh, acc0, 0, 0, 0);
            acc1 = __builtin_amdgcn_mfma_f32_16x16x32_bf16(al, xh, acc1, 0, 0, 0);
            acc2 = __builtin_amdgcn_mfma_f32_16x16x32_bf16(ah, xl, acc2, 0, 0, 0);
        }

        // ---- Euler update (xo register-carried) ----
        float4 nv;
        nv.x = c0*xo.x + STEP_F*(acc0[0] + acc1[0] + acc2[0] + bv.x);
        nv.y = c0*xo.y + STEP_F*(acc0[1] + acc1[1] + acc2[1] + bv.y);
        nv.z = c0*xo.z + STEP_F*(acc0[2] + acc1[2] + acc2[2] + bv.z);
        nv.w = c0*xo.w + STEP_F*(acc0[3] + acc1[3] + acc2[3] + bv.w);
        xo = nv;

        // ---- publish == trajectory write (atomic 8B, MALL-coherent) ----
        {
            float* op = out + (size_t)ccol*OUT_TN + (size_t)t*NN + crow;
            float2 p0 = {nv.x, nv.y}, p1 = {nv.z, nv.w};
            __hip_atomic_store(reinterpret_cast<ull*>(op),
                               __builtin_bit_cast(ull, p0),
                               __ATOMIC_RELAXED, __HIP_MEMORY_SCOPE_AGENT);
            __hip_atomic_store(reinterpret_cast<ull*>(op) + 1,
                               __builtin_bit_cast(ull, p1),
                               __ATOMIC_RELAXED, __HIP_MEMORY_SCOPE_AGENT);
        }

        if (t < TMAXN - 1) {
            // ---- own rows -> next LDS buffer straight from registers ----
            u16x4 hv, lv;
            float v4[4] = {nv.x, nv.y, nv.z, nv.w};
#pragma unroll
            for (int j = 0; j < 4; ++j) {
                float x = fmaxf(v4[j], 0.f);
                __bf16 hh = (__bf16)x;
                hv[j] = __builtin_bit_cast(unsigned short, hh);
                lv[j] = __builtin_bit_cast(unsigned short, (__bf16)(x - (float)hh));
            }
            *reinterpret_cast<u16x4*>(&xs[nxtoff + own_ad]) = hv;
            *reinterpret_cast<u16x4*>(&xs[16384 + nxtoff + own_ad]) = lv;

            __syncthreads();             // drains publish acks (vmcnt) + LDS
            if (tid == 0) {
                __hip_atomic_store(&fline[rg], (unsigned)t,
                                   __ATOMIC_RELAXED, __HIP_MEMORY_SCOPE_AGENT);
            }

            // ---- poll the dom's 8-flag line (4x8B broadcast loads) ----
            unsigned tu = (unsigned)t;
            for (;;) {
                ull a = __hip_atomic_load(reinterpret_cast<ull*>(fline) + 0, __ATOMIC_RELAXED, __HIP_MEMORY_SCOPE_AGENT);
                ull b = __hip_atomic_load(reinterpret_cast<ull*>(fline) + 1, __ATOMIC_RELAXED, __HIP_MEMORY_SCOPE_AGENT);
                ull c = __hip_atomic_load(reinterpret_cast<ull*>(fline) + 2, __ATOMIC_RELAXED, __HIP_MEMORY_SCOPE_AGENT);
                ull d = __hip_atomic_load(reinterpret_cast<ull*>(fline) + 3, __ATOMIC_RELAXED, __HIP_MEMORY_SCOPE_AGENT);
                unsigned g0 = (unsigned)a, g1 = (unsigned)(a >> 32);
                unsigned g2 = (unsigned)b, g3 = (unsigned)(b >> 32);
                unsigned g4 = (unsigned)c, g5 = (unsigned)(c >> 32);
                unsigned g6 = (unsigned)d, g7 = (unsigned)(d >> 32);
                bool ok = (rg == 0 || g0 >= tu) && (rg == 1 || g1 >= tu)
                       && (rg == 2 || g2 >= tu) && (rg == 3 || g3 >= tu)
                       && (rg == 4 || g4 >= tu) && (rg == 5 || g5 >= tu)
                       && (rg == 6 || g6 >= tu) && (rg == 7 || g7 >= tu);
                if (ok) break;
                __builtin_amdgcn_s_sleep(1);
            }
            asm volatile("" ::: "memory");
            __builtin_amdgcn_sched_barrier(0);

            // ---- fetch 7 siblings' x_t from out (14 x 8B, pipelined) ----
            ull pv[14];
            const float* obase = out + (size_t)(dom*16 + sc)*OUT_TN + (size_t)t*NN;
#pragma unroll
            for (int rr = 0; rr < 7; ++rr) {
                int rgs = (rg + 1 + rr) & 7;
                const ull* p = reinterpret_cast<const ull*>(obase + rgs*64 + kl*2);
                pv[rr*2+0] = __hip_atomic_load(p,      __ATOMIC_RELAXED, __HIP_MEMORY_SCOPE_AGENT);
                pv[rr*2+1] = __hip_atomic_load(p + 16, __ATOMIC_RELAXED, __HIP_MEMORY_SCOPE_AGENT);
            }

            // ---- relu+split+unpack into next LDS buffer ----
#pragma unroll
            for (int rr = 0; rr < 7; ++rr) {
                int rgs = (rg + 1 + rr) & 7;
#pragma unroll
                for (int q = 0; q < 2; ++q) {
                    float2 f = __builtin_bit_cast(float2, pv[rr*2+q]);
                    float a0 = fmaxf(f.x, 0.f), a1 = fmaxf(f.y, 0.f);
                    __bf16 h0 = (__bf16)a0, h1 = (__bf16)a1;
                    __bf16 l0 = (__bf16)(a0 - (float)h0), l1 = (__bf16)(a1 - (float)h1);
                    unsigned hw = (unsigned)__builtin_bit_cast(unsigned short, h0)
                                | ((unsigned)__builtin_bit_cast(unsigned short, h1) << 16);
                    unsigned lw = (unsigned)__builtin_bit_cast(unsigned short, l0)
                                | ((unsigned)__builtin_bit_cast(unsigned short, l1) << 16);
                    int r = rgs*64 + (kl + q*16)*2;
                    int ad = nxtoff + scb + ((2*r) ^ ssw);
                    *reinterpret_cast<unsigned*>(&xs[ad]) = hw;
                    *reinterpret_cast<unsigned*>(&xs[16384 + ad]) = lw;
                }
            }
        }
    }
}

// ---------------- host ----------------

extern "C" void kernel_launch(void* const* d_in, const int* in_sizes, int n_in,
                              void* d_out, int out_size, void* d_ws, size_t ws_size,
                              hipStream_t stream)
{
    const float* X0        = (const float*)d_in[0];
    const float* A_raw     = (const float*)d_in[1];
    const float* Theta_raw = (const float*)d_in[2];
    const float* U_raw     = (const float*)d_in[3];
    const float* Sigma_raw = (const float*)d_in[4];
    const float* V_raw     = (const float*)d_in[5];
    const float* bx_raw    = (const float*)d_in[6];
    float* out = (float*)d_out;

    // expm scratch lives in d_out (256 MB; fully overwritten by the steps after)
    float* S   = out;               // [2][512][512]
    float* S2  = out + 1*MAT2;
    float* S3  = out + 2*MAT2;
    float* S4  = out + 3*MAT2;
    float* Q2b = out + 4*MAT2;
    float* Q1b = out + 5*MAT2;
    float* Q0b = out + 6*MAT2;      // 7*MAT2*4B = 14.7 MB << 256 MB

    // persistent storage in d_ws (~1.6 MB)
    char* wsc = (char*)d_ws;
    __bf16* Bh = (__bf16*)wsc;                        // 512 KB
    __bf16* Bl = (__bf16*)(wsc + 524288);             // 512 KB
    float* xb0 = (float*)(wsc + 1048576);             // 256 KB
    float* params = (float*)(wsc + 1048576 + 262144);
    float* theta  = params + 64;
    float* sigma  = theta + 512;
    float* bx     = sigma + 512;
    unsigned* flg = (unsigned*)(wsc + 1048576 + 262144 + 8192);  // 512 B

    prep_params<<<1, 512, 0, stream>>>(A_raw, Theta_raw, Sigma_raw, bx_raw,
                                       params, theta, sigma, bx);
    build_S<<<MAT2/256, 256, 0, stream>>>(U_raw, V_raw, S);

    // Paterson-Stockmeyer order-12 Taylor: P = Q0 + S4*(Q1 + S4*Q2)
    mm64<<<dim3(8,8,2), 256, 0, stream>>>(S,  S,   S2,  0);   // S2 = S*S
    mm64<<<dim3(8,8,2), 256, 0, stream>>>(S2, S,   S3,  0);   // S3 = S2*S
    mm64<<<dim3(8,8,2), 256, 0, stream>>>(S2, S2,  S4,  0);   // S4 = S2*S2
    combo3<<<MAT2/256, 256, 0, stream>>>(S, S2, S3, S4, Q0b, Q1b, Q2b);
    mm64<<<dim3(8,8,2), 256, 0, stream>>>(S4, Q2b, Q1b, 1);   // R = Q1 + S4*Q2
    mm64<<<dim3(8,8,2), 256, 0, stream>>>(S4, Q1b, Q0b, 1);   // P = Q0 + S4*R
    // 5 squarings
    float* Pa = Q0b; float* Pb = Q2b;
    for (int q = 0; q < 5; ++q) {
        mm64<<<dim3(8,8,2), 256, 0, stream>>>(Pa, Pa, Pb, 0);
        float* t2 = Pa; Pa = Pb; Pb = t2;
    }
    // Pa = [E_U ; E_V]

    scale_transpose<<<MATSZ/256, 256, 0, stream>>>(Pa, Pa + MATSZ, sigma,
                                                   S, S + MATSZ);     // Asc, VT
    mm64<<<dim3(8,8,1), 256, 0, stream>>>(S, S + MATSZ, S2, 0);       // Bmm = Asc*VT
    finalize_Bsplit<<<MATSZ/256, 256, 0, stream>>>(S2, theta, Bh, Bl);

    init_x<<<BSZ*NN/256, 256, 0, stream>>>(X0, xb0, out);

    // zero flags each launch (replay safety)
    hipMemsetAsync(flg, 0, 512, stream);

    void* args[] = { (void*)&xb0, (void*)&Bh, (void*)&Bl,
                     (void*)&params, (void*)&bx, (void*)&out, (void*)&flg };
    hipLaunchCooperativeKernel((const void*)step_persist, dim3(NBLOCKS), dim3(256),
                               args, 0, stream);
}

// Round 11
// 3024.206 us; speedup vs baseline: 1.3171x; 1.3171x over previous
//
#include <hip/hip_runtime.h>
#include <cstddef>

#define NN 512
#define BSZ 128
#define TMAXN 1024
#define STEP_F 0.01f
#define EPS_F 1e-05f
#define MATSZ (NN*NN)        // 262144
#define MAT2 (2*MATSZ)
#define OUT_TN (TMAXN*NN)    // 524288
#define SKEW_SCALE 0.03125f  // 2^-5, 5 squarings
#define NBLOCKS 64           // 16 domains x 4 row-groups
#define NDOM 16
#define DCOLS 8

typedef __bf16 bf16x8 __attribute__((ext_vector_type(8)));
typedef float f32x4 __attribute__((ext_vector_type(4)));
typedef unsigned short u16x4 __attribute__((ext_vector_type(4)));
typedef unsigned u32x4 __attribute__((ext_vector_type(4)));
typedef unsigned long long ull;

// ---------------- small prep kernels ----------------

__global__ void prep_params(const float* __restrict__ A_raw,
                            const float* __restrict__ Theta_raw,
                            const float* __restrict__ Sigma_raw,
                            const float* __restrict__ bx_raw,
                            float* __restrict__ params,
                            float* __restrict__ theta,
                            float* __restrict__ sigma,
                            float* __restrict__ bx)
{
    int i = threadIdx.x;  // 512 threads
    if (i == 0) params[0] = fabsf(A_raw[0]) + EPS_F;
    theta[i] = fabsf(Theta_raw[i*NN + i]) + EPS_F;
    float sd = Sigma_raw[i*NN + i];
    sigma[i] = expf(-sd*sd);           // (1/G)*exp(-d^2), G=1
    bx[i] = bx_raw[i];
}

// S[z][i][j] = skew(raw_z)[i][j] * 2^-5
__global__ void build_S(const float* __restrict__ U_raw,
                        const float* __restrict__ V_raw,
                        float* __restrict__ S)
{
    int idx = blockIdx.x * 256 + threadIdx.x;   // 0 .. MAT2-1
    int z = idx >> 18;
    int rem = idx & (MATSZ - 1);
    int i = rem >> 9;
    int j = rem & (NN - 1);
    const float* src = (z == 0) ? U_raw : V_raw;
    float v = 0.0f;
    if (i < j)      v = src[i*NN + j];
    else if (i > j) v = -src[j*NN + i];
    S[idx] = v * SKEW_SCALE;
}

// ---------------- fp32 matmul: C = A*B (+C if accflag), batched over z ----------------
// 64x64 tile (r9-proven), 256 threads, 4x4/thread, BK=16; 128 blocks/launch
__global__ __launch_bounds__(256) void mm64(const float* __restrict__ A,
                                            const float* __restrict__ Bm,
                                            float* __restrict__ C,
                                            int accflag)
{
    int z = blockIdx.z;
    A  += (size_t)z * MATSZ;
    Bm += (size_t)z * MATSZ;
    C  += (size_t)z * MATSZ;

    __shared__ float As[16][68];   // [k][m], padded
    __shared__ float Bs[16][68];   // [k][n]

    int tid = threadIdx.x;
    int tx = tid & 15;
    int ty = tid >> 4;
    int row0 = blockIdx.y * 64;
    int col0 = blockIdx.x * 64;

    float acc[4][4] = {{0.f}};

    for (int k0 = 0; k0 < NN; k0 += 16) {
        {
            int i = tid >> 2;             // 0..63 row
            int j = (tid & 3) << 2;       // 0,4,8,12 k
            float4 av = *reinterpret_cast<const float4*>(&A[(size_t)(row0 + i)*NN + k0 + j]);
            As[j+0][i] = av.x; As[j+1][i] = av.y; As[j+2][i] = av.z; As[j+3][i] = av.w;
        }
        {
            int bi = tid >> 4;            // 0..15 k
            int bj = (tid & 15) << 2;     // 0..60 col
            float4 bv = *reinterpret_cast<const float4*>(&Bm[(size_t)(k0 + bi)*NN + col0 + bj]);
            *reinterpret_cast<float4*>(&Bs[bi][bj]) = bv;
        }
        __syncthreads();
#pragma unroll
        for (int k = 0; k < 16; ++k) {
            float a0 = As[k][ty], a1 = As[k][ty+16], a2 = As[k][ty+32], a3 = As[k][ty+48];
            float b0 = Bs[k][tx], b1 = Bs[k][tx+16], b2 = Bs[k][tx+32], b3 = Bs[k][tx+48];
            acc[0][0] += a0*b0; acc[0][1] += a0*b1; acc[0][2] += a0*b2; acc[0][3] += a0*b3;
            acc[1][0] += a1*b0; acc[1][1] += a1*b1; acc[1][2] += a1*b2; acc[1][3] += a1*b3;
            acc[2][0] += a2*b0; acc[2][1] += a2*b1; acc[2][2] += a2*b2; acc[2][3] += a2*b3;
            acc[3][0] += a3*b0; acc[3][1] += a3*b1; acc[3][2] += a3*b2; acc[3][3] += a3*b3;
        }
        __syncthreads();
    }

#pragma unroll
    for (int mi = 0; mi < 4; ++mi) {
        size_t r = (size_t)(row0 + ty + 16*mi);
#pragma unroll
        for (int mj = 0; mj < 4; ++mj) {
            size_t cidx = r*NN + col0 + tx + 16*mj;
            float v = acc[mi][mj];
            if (accflag) v += C[cidx];
            C[cidx] = v;
        }
    }
}

// Q0/Q1/Q2 for Paterson-Stockmeyer order-12 Taylor of exp
__global__ void combo3(const float* __restrict__ S, const float* __restrict__ S2,
                       const float* __restrict__ S3, const float* __restrict__ S4,
                       float* __restrict__ Q0, float* __restrict__ Q1,
                       float* __restrict__ Q2)
{
    const float C0 = 1.0f, C1 = 1.0f, C2 = 0.5f, C3 = 1.0f/6.0f;
    const float C4 = 1.0f/24.0f, C5 = 1.0f/120.0f, C6 = 1.0f/720.0f, C7 = 1.0f/5040.0f;
    const float C8 = 1.0f/40320.0f, C9 = 1.0f/362880.0f, C10 = 1.0f/3628800.0f;
    const float C11 = 1.0f/39916800.0f, C12 = 1.0f/479001600.0f;
    int idx = blockIdx.x * 256 + threadIdx.x;   // 0 .. MAT2-1
    int rem = idx & (MATSZ - 1);
    int i = rem >> 9;
    int j = rem & (NN - 1);
    float d = (i == j) ? 1.0f : 0.0f;
    float s = S[idx], s2 = S2[idx], s3 = S3[idx], s4 = S4[idx];
    Q0[idx] = C0*d + C1*s + C2*s2 + C3*s3;
    Q1[idx] = C4*d + C5*s + C6*s2 + C7*s3;
    Q2[idx] = C8*d + C9*s + C10*s2 + C11*s3 + C12*s4;
}

// Asc[i][j] = E_U[i][j]*sigma[j];  VT[i][j] = E_V[j][i]
__global__ void scale_transpose(const float* __restrict__ EU,
                                const float* __restrict__ EV,
                                const float* __restrict__ sigma,
                                float* __restrict__ Asc,
                                float* __restrict__ VT)
{
    int idx = blockIdx.x * 256 + threadIdx.x;   // 0..MATSZ-1
    int i = idx >> 9;
    int j = idx & (NN - 1);
    Asc[idx] = EU[idx] * sigma[j];
    VT[idx]  = EV[j*NN + i];
}

// Bh/Bl[r][k]: bf16 hi/lo split of B[r][k] = Bmm[r][k]*theta[k]/theta[r]
__global__ void finalize_Bsplit(const float* __restrict__ Bmm,
                                const float* __restrict__ theta,
                                __bf16* __restrict__ Bh,
                                __bf16* __restrict__ Bl)
{
    int idx = blockIdx.x * 256 + threadIdx.x;   // 0..MATSZ-1
    int r = idx >> 9;
    int k = idx & (NN - 1);
    float v = Bmm[idx] * theta[k] / theta[r];
    __bf16 h = (__bf16)v;
    Bh[idx] = h;
    Bl[idx] = (__bf16)(v - (float)h);
}

// xb0 = X0 (layout [b][n]); out[b, 0, n] = X0[b][n]
__global__ void init_x(const float* __restrict__ X0,
                       float* __restrict__ xb0,
                       float* __restrict__ out)
{
    int idx = blockIdx.x * 256 + threadIdx.x;   // 0..65535
    int b = idx >> 9;
    int n = idx & (NN - 1);
    float v = X0[idx];
    xb0[idx] = v;
    out[(size_t)b * OUT_TN + n] = v;
}

// ---------------- persistent step kernel (cooperative, r8-proven) ----------------
// 64 blocks x 512 threads. dom = bid>>2 owns 8 batch cols; rg = bid&3 owns
// 128 rows. MFMA tile is 16 cols wide; cols 8..15 are zero padding; all
// per-column side effects (LDS own-write, pubstage, out stores) gated on
// real = (c_l < 8).
// Exchange: hi|lo packed u32, staged via LDS pubstage -> wave-contiguous 8B
// atomic stores (full 64B lines). syncthreads drains; tid0 flags; consumers
// poll one 16B flag line then fetch 3x8B payload/thread.
__global__ __launch_bounds__(512, 2) void step_persist(
    const float* __restrict__ x0g,    // [128][512] state at t=0
    const __bf16* __restrict__ Bh,    // [512][512] row-major [r][k]
    const __bf16* __restrict__ Bl,
    const float* __restrict__ params,
    const float* __restrict__ bx,
    float* __restrict__ out,
    ull* __restrict__ pay,            // [2][16][4][512] ull  (512 KB)
    unsigned* __restrict__ flg)       // [2][16][16] u32      (2 KB, 64B/line)
{
    // LDS: 2 x (hi 16KB + lo 16KB) x-buffers + 4KB pubstage
    __shared__ char xs[65536];
    __shared__ unsigned pubstage[1024];   // [col(8)][row(128)] u32 = hi|lo<<16
    int tid = threadIdx.x;
    int bid = blockIdx.x;
    int dom = bid >> 2;
    int rg  = bid & 3;
    int w = tid >> 6;
    int l = tid & 63;

    // ---- preload A-fragments (B rows, this block's 128 rows) ----
    int r0 = rg*128 + w*16;
    int arow = l & 15;
    int kch  = l >> 4;
    f32x4 ah[16], al[16];
    {
        const __bf16* bhrow = Bh + (size_t)(r0 + arow)*NN + kch*8;
        const __bf16* blrow = Bl + (size_t)(r0 + arow)*NN + kch*8;
#pragma unroll
        for (int ks = 0; ks < 16; ++ks) {
            ah[ks] = *reinterpret_cast<const f32x4*>(bhrow + ks*32);
            al[ks] = *reinterpret_cast<const f32x4*>(blrow + ks*32);
        }
    }
    // pin attempt: volatile asm tie (can't be rematerialized)
#pragma unroll
    for (int ks = 0; ks < 16; ++ks) {
        asm volatile("" : "+v"(ah[ks]));
        asm volatile("" : "+v"(al[ks]));
    }

    int c_l  = l & 15;
    int real = (c_l < DCOLS);
    int crow = r0 + (l >> 4)*4;          // global row, multiple of 4
    int crow_loc = w*16 + (l >> 4)*4;    // row within block [0,128)
    int ccol = dom*DCOLS + (c_l & 7);
    float c0 = 1.0f - STEP_F * (params[0]);
    float4 bv = *reinterpret_cast<const float4*>(&bx[crow]);
    int xsw   = (c_l & 7) << 4;
    int xfrag = c_l * 1024;
    int own_ad = xfrag + ((2*crow) ^ xsw);   // 8B-aligned

    // prologue staging mapping
    int sc = tid >> 5;                   // LDS col 0..15
    int ks_l = tid & 31;
    int scb = sc * 1024;
    int ssw = (sc & 7) << 4;

    // ---- prologue: stage x0 into buf0 (real cols), zero garbage cols ----
    {
        const float* src = x0g + (size_t)(dom*DCOLS + (sc & 7))*NN;
#pragma unroll
        for (int i = 0; i < 16; ++i) {
            int k = i*32 + ks_l;
            float x = (sc < 8) ? fmaxf(src[k], 0.0f) : 0.0f;
            __bf16 hh = (__bf16)x;
            __bf16 ll = (__bf16)(x - (float)hh);
            int ad = scb + ((2*k) ^ ssw);
            *reinterpret_cast<__bf16*>(&xs[ad]) = hh;
            *reinterpret_cast<__bf16*>(&xs[16384 + ad]) = ll;
            if (sc >= 8) {   // zero garbage cols of buf1 too
                *reinterpret_cast<__bf16*>(&xs[32768 + ad]) = hh;
                *reinterpret_cast<__bf16*>(&xs[49152 + ad]) = ll;
            }
        }
    }
    float4 xo = *reinterpret_cast<const float4*>(&x0g[(size_t)ccol*NN + crow]);

    for (int t = 1; t < TMAXN; ++t) {
        __syncthreads();                 // buf[(t-1)&1] fully staged

        int curoff = ((t-1) & 1) * 32768;
        int nxtoff = (t & 1) * 32768;

        // ---- MFMA: acc = B * relu(x_{t-1}) with hi/lo compensation ----
        f32x4 acc0 = {0,0,0,0}, acc1 = {0,0,0,0}, acc2 = {0,0,0,0};
#pragma unroll
        for (int ks = 0; ks < 16; ++ks) {
            int ad = curoff + xfrag + (((ks*32 + kch*8) * 2) ^ xsw);
            bf16x8 xh = __builtin_bit_cast(bf16x8, *reinterpret_cast<const f32x4*>(&xs[ad]));
            bf16x8 xl = __builtin_bit_cast(bf16x8, *reinterpret_cast<const f32x4*>(&xs[16384 + ad]));
            acc0 = __builtin_amdgcn_mfma_f32_16x16x32_bf16(__builtin_bit_cast(bf16x8, ah[ks]), xh, acc0, 0, 0, 0);
            acc1 = __builtin_amdgcn_mfma_f32_16x16x32_bf16(__builtin_bit_cast(bf16x8, al[ks]), xh, acc1, 0, 0, 0);
            acc2 = __builtin_amdgcn_mfma_f32_16x16x32_bf16(__builtin_bit_cast(bf16x8, ah[ks]), xl, acc2, 0, 0, 0);
        }

        // ---- Euler update (xo register-carried) ----
        float4 nv;
        nv.x = c0*xo.x + STEP_F*(acc0[0] + acc1[0] + acc2[0] + bv.x);
        nv.y = c0*xo.y + STEP_F*(acc0[1] + acc1[1] + acc2[1] + bv.y);
        nv.z = c0*xo.z + STEP_F*(acc0[2] + acc1[2] + acc2[2] + bv.z);
        nv.w = c0*xo.w + STEP_F*(acc0[3] + acc1[3] + acc2[3] + bv.w);
        xo = nv;

        if (t < TMAXN - 1) {
            // ---- relu+split once; own rows -> LDS buf[nxt] + pubstage ----
            float v4[4] = {nv.x, nv.y, nv.z, nv.w};
            u16x4 hv, lv;
            u32x4 pk;
#pragma unroll
            for (int j = 0; j < 4; ++j) {
                float x = fmaxf(v4[j], 0.0f);
                __bf16 hh = (__bf16)x;
                __bf16 ll = (__bf16)(x - (float)hh);
                unsigned short hb = __builtin_bit_cast(unsigned short, hh);
                unsigned short lb = __builtin_bit_cast(unsigned short, ll);
                hv[j] = hb; lv[j] = lb;
                pk[j] = (unsigned)hb | ((unsigned)lb << 16);
            }
            if (real) {
                *reinterpret_cast<u16x4*>(&xs[nxtoff + own_ad]) = hv;
                *reinterpret_cast<u16x4*>(&xs[16384 + nxtoff + own_ad]) = lv;
                *reinterpret_cast<u32x4*>(&pubstage[c_l*128 + crow_loc]) = pk;
            }

            __syncthreads();             // pubstage complete (LDS)

            // ---- publish: wave-contiguous 8B atomic stores (full lines) ----
            int par = t & 1;
            ull pv_own = reinterpret_cast<ull*>(pubstage)[tid];
            size_t pubBase = ((size_t)(par*NDOM + dom)*4 + rg) * 512;
            __hip_atomic_store(&pay[pubBase + tid], pv_own,
                               __ATOMIC_RELAXED, __HIP_MEMORY_SCOPE_AGENT);

            __syncthreads();             // drain vmcnt: publishes ack'd
            unsigned* fline = flg + (size_t)(par*NDOM + dom) * 16;
            if (tid == 0) {
                __hip_atomic_store(&fline[rg], (unsigned)t,
                                   __ATOMIC_RELAXED, __HIP_MEMORY_SCOPE_AGENT);
            }
            // trajectory write overlaps the poll window (REAL COLS ONLY)
            if (real) {
                *reinterpret_cast<float4*>(&out[(size_t)ccol*OUT_TN + (size_t)t*NN + crow]) = nv;
            }

            // ---- poll sibling flags (one 16B line) ----
            unsigned tu = (unsigned)t;
            for (;;) {
                ull f01 = __hip_atomic_load((ull*)fline,     __ATOMIC_RELAXED, __HIP_MEMORY_SCOPE_AGENT);
                ull f23 = __hip_atomic_load((ull*)fline + 1, __ATOMIC_RELAXED, __HIP_MEMORY_SCOPE_AGENT);
                unsigned f0 = (unsigned)f01, f1 = (unsigned)(f01 >> 32);
                unsigned f2 = (unsigned)f23, f3 = (unsigned)(f23 >> 32);
                bool ok = (rg == 0 || f0 >= tu) && (rg == 1 || f1 >= tu)
                       && (rg == 2 || f2 >= tu) && (rg == 3 || f3 >= tu);
                if (ok) break;
                __builtin_amdgcn_s_sleep(1);
            }
            asm volatile("" ::: "memory");
            __builtin_amdgcn_sched_barrier(0);

            // ---- fetch 3 sibling payloads (3 x 8B/thread, pipelined) ----
            ull pv[3];
            int rgs[3];
#pragma unroll
            for (int rr = 0; rr < 3; ++rr) {
                rgs[rr] = (rg + 1 + rr) & 3;
                size_t b = ((size_t)(par*NDOM + dom)*4 + rgs[rr]) * 512;
                pv[rr] = __hip_atomic_load(&pay[b + tid],
                             __ATOMIC_RELAXED, __HIP_MEMORY_SCOPE_AGENT);
            }

            // ---- unpack into buf[nxt]: col=tid>>6, rows 2*(tid&63)(+1) ----
            int ucol = tid >> 6;         // 0..7
            int urow = (tid & 63) * 2;
            int usw = (ucol & 7) << 4;
            int ubase = nxtoff + ucol*1024;
#pragma unroll
            for (int rr = 0; rr < 3; ++rr) {
                int row = rgs[rr]*128 + urow;
                unsigned a = (unsigned)pv[rr];
                unsigned b2 = (unsigned)(pv[rr] >> 32);
                int ad0 = ubase + ((2*row) ^ usw);
                int ad1 = ubase + ((2*(row+1)) ^ usw);
                *reinterpret_cast<unsigned short*>(&xs[ad0]) = (unsigned short)a;
                *reinterpret_cast<unsigned short*>(&xs[16384 + ad0]) = (unsigned short)(a >> 16);
                *reinterpret_cast<unsigned short*>(&xs[ad1]) = (unsigned short)b2;
                *reinterpret_cast<unsigned short*>(&xs[16384 + ad1]) = (unsigned short)(b2 >> 16);
            }
        } else {
            if (real) {
                *reinterpret_cast<float4*>(&out[(size_t)ccol*OUT_TN + (size_t)t*NN + crow]) = nv;
            }
        }
    }
}

// ---------------- host ----------------

extern "C" void kernel_launch(void* const* d_in, const int* in_sizes, int n_in,
                              void* d_out, int out_size, void* d_ws, size_t ws_size,
                              hipStream_t stream)
{
    const float* X0        = (const float*)d_in[0];
    const float* A_raw     = (const float*)d_in[1];
    const float* Theta_raw = (const float*)d_in[2];
    const float* U_raw     = (const float*)d_in[3];
    const float* Sigma_raw = (const float*)d_in[4];
    const float* V_raw     = (const float*)d_in[5];
    const float* bx_raw    = (const float*)d_in[6];
    float* out = (float*)d_out;

    // expm scratch lives in d_out (256 MB; fully overwritten by the steps after)
    float* S   = out;               // [2][512][512]
    float* S2  = out + 1*MAT2;
    float* S3  = out + 2*MAT2;
    float* S4  = out + 3*MAT2;
    float* Q2b = out + 4*MAT2;
    float* Q1b = out + 5*MAT2;
    float* Q0b = out + 6*MAT2;      // 7*MAT2*4B = 14.7 MB << 256 MB

    // persistent storage in d_ws (~2.1 MB)
    char* wsc = (char*)d_ws;
    __bf16* Bh = (__bf16*)wsc;                        // 512 KB
    __bf16* Bl = (__bf16*)(wsc + 524288);             // 512 KB
    float* xb0 = (float*)(wsc + 1048576);             // 256 KB
    float* params = (float*)(wsc + 1048576 + 262144);
    float* theta  = params + 64;
    float* sigma  = theta + 512;
    float* bx     = sigma + 512;
    ull* pay      = (ull*)(wsc + 1572864);            // 512 KB
    unsigned* flg = (unsigned*)(wsc + 1572864 + 524288);  // 2 KB

    prep_params<<<1, 512, 0, stream>>>(A_raw, Theta_raw, Sigma_raw, bx_raw,
                                       params, theta, sigma, bx);
    build_S<<<MAT2/256, 256, 0, stream>>>(U_raw, V_raw, S);

    // Paterson-Stockmeyer order-12 Taylor: P = Q0 + S4*(Q1 + S4*Q2)
    mm64<<<dim3(8,8,2), 256, 0, stream>>>(S,  S,   S2,  0);   // S2 = S*S
    mm64<<<dim3(8,8,2), 256, 0, stream>>>(S2, S,   S3,  0);   // S3 = S2*S
    mm64<<<dim3(8,8,2), 256, 0, stream>>>(S2, S2,  S4,  0);   // S4 = S2*S2
    combo3<<<MAT2/256, 256, 0, stream>>>(S, S2, S3, S4, Q0b, Q1b, Q2b);
    mm64<<<dim3(8,8,2), 256, 0, stream>>>(S4, Q2b, Q1b, 1);   // R = Q1 + S4*Q2
    mm64<<<dim3(8,8,2), 256, 0, stream>>>(S4, Q1b, Q0b, 1);   // P = Q0 + S4*R
    // 5 squarings
    float* Pa = Q0b; float* Pb = Q2b;
    for (int q = 0; q < 5; ++q) {
        mm64<<<dim3(8,8,2), 256, 0, stream>>>(Pa, Pa, Pb, 0);
        float* t2 = Pa; Pa = Pb; Pb = t2;
    }
    // Pa = [E_U ; E_V]

    scale_transpose<<<MATSZ/256, 256, 0, stream>>>(Pa, Pa + MATSZ, sigma,
                                                   S, S + MATSZ);     // Asc, VT
    mm64<<<dim3(8,8,1), 256, 0, stream>>>(S, S + MATSZ, S2, 0);       // Bmm = Asc*VT
    finalize_Bsplit<<<MATSZ/256, 256, 0, stream>>>(S2, theta, Bh, Bl);

    init_x<<<BSZ*NN/256, 256, 0, stream>>>(X0, xb0, out);

    // zero flags each launch (replay safety)
    hipMemsetAsync(flg, 0, 2048, stream);

    void* args[] = { (void*)&xb0, (void*)&Bh, (void*)&Bl,
                     (void*)&params, (void*)&bx, (void*)&out,
                     (void*)&pay, (void*)&flg };
    hipLaunchCooperativeKernel((const void*)step_persist, dim3(NBLOCKS), dim3(512),
                               args, 0, stream);
}